// Round 3
// baseline (828.907 us; speedup 1.0000x reference)
//
#include <hip/hip_runtime.h>

// Haar DWT, fp32, input (8,64,512,512) -> 4 bands each (8,64,256,256).
// Pure memory-bound streaming kernel. Each work item processes a 2x8 input
// patch (four 16B loads) and emits one 16B store to each of the four bands.
// All memory ops are 16 B/lane, non-temporal (streaming, no reuse).

typedef float f32x4 __attribute__((ext_vector_type(4)));

#define N_IMG   512          // 8*64
#define IN_W    512
#define IN_H    512
#define OUT_W   256
#define OUT_H   256
#define BAND    ((size_t)N_IMG * OUT_W * OUT_H)       // elems per band
#define ITEMS   (N_IMG * OUT_H * (OUT_W / 4))         // 8,388,608 work items

__global__ __launch_bounds__(256) void haar_dwt_kernel(
        const float* __restrict__ x, float* __restrict__ out) {
    float* __restrict__ o_ll = out;
    float* __restrict__ o_lh = out + BAND;
    float* __restrict__ o_hl = out + 2 * BAND;
    float* __restrict__ o_hh = out + 3 * BAND;

    const int stride = gridDim.x * blockDim.x;
    for (int t = blockIdx.x * blockDim.x + threadIdx.x; t < ITEMS; t += stride) {
        const int j    = t & 63;           // which pair-of-f32x4 in the row
        const int orow = (t >> 6) & 255;   // output row
        const int img  = t >> 14;          // image index

        // input rows 2*orow, 2*orow+1; cols 8j .. 8j+7
        const size_t in_base = (size_t)img * (IN_W * IN_H) + (size_t)(2 * orow) * IN_W;
        const f32x4* xt = reinterpret_cast<const f32x4*>(x + in_base) + 2 * j;
        const f32x4 t0 = __builtin_nontemporal_load(xt);                 // even row, cols 8j..8j+3
        const f32x4 t1 = __builtin_nontemporal_load(xt + 1);             // even row, cols 8j+4..8j+7
        const f32x4 b0 = __builtin_nontemporal_load(xt + IN_W / 4);      // odd row
        const f32x4 b1 = __builtin_nontemporal_load(xt + IN_W / 4 + 1);

        f32x4 ll, lh, hl, hh;
        // pair p: a=top[2p] b=top[2p+1] c=bot[2p] d=bot[2p+1]
        {   // p0
            const float st = t0[0] + t0[1], dt = t0[1] - t0[0];
            const float sb = b0[0] + b0[1], db = b0[1] - b0[0];
            ll[0] = (st + sb) * 0.5f; lh[0] = (sb - st) * 0.5f;
            hl[0] = (dt + db) * 0.5f; hh[0] = (db - dt) * 0.5f;
        }
        {   // p1
            const float st = t0[2] + t0[3], dt = t0[3] - t0[2];
            const float sb = b0[2] + b0[3], db = b0[3] - b0[2];
            ll[1] = (st + sb) * 0.5f; lh[1] = (sb - st) * 0.5f;
            hl[1] = (dt + db) * 0.5f; hh[1] = (db - dt) * 0.5f;
        }
        {   // p2
            const float st = t1[0] + t1[1], dt = t1[1] - t1[0];
            const float sb = b1[0] + b1[1], db = b1[1] - b1[0];
            ll[2] = (st + sb) * 0.5f; lh[2] = (sb - st) * 0.5f;
            hl[2] = (dt + db) * 0.5f; hh[2] = (db - dt) * 0.5f;
        }
        {   // p3
            const float st = t1[2] + t1[3], dt = t1[3] - t1[2];
            const float sb = b1[2] + b1[3], db = b1[3] - b1[2];
            ll[3] = (st + sb) * 0.5f; lh[3] = (sb - st) * 0.5f;
            hl[3] = (dt + db) * 0.5f; hh[3] = (db - dt) * 0.5f;
        }

        const size_t oi = (size_t)img * (OUT_W * OUT_H) + (size_t)orow * OUT_W + 4 * j;
        __builtin_nontemporal_store(ll, reinterpret_cast<f32x4*>(o_ll + oi));
        __builtin_nontemporal_store(lh, reinterpret_cast<f32x4*>(o_lh + oi));
        __builtin_nontemporal_store(hl, reinterpret_cast<f32x4*>(o_hl + oi));
        __builtin_nontemporal_store(hh, reinterpret_cast<f32x4*>(o_hh + oi));
    }
}

extern "C" void kernel_launch(void* const* d_in, const int* in_sizes, int n_in,
                              void* d_out, int out_size, void* d_ws, size_t ws_size,
                              hipStream_t stream) {
    const float* x = (const float*)d_in[0];
    float* out = (float*)d_out;
    const int block = 256;
    const int grid = 2048;  // grid-stride; ~8 blocks/CU across 256 CUs
    haar_dwt_kernel<<<grid, block, 0, stream>>>(x, out);
}